// Round 6
// baseline (497.152 us; speedup 1.0000x reference)
//
#include <hip/hip_runtime.h>
#include <stdint.h>

typedef __bf16 bf16x8_t __attribute__((ext_vector_type(8)));
typedef float f32x4_t __attribute__((ext_vector_type(4)));

#define DEV __device__ __forceinline__

DEV unsigned short f2bf(float f) {
  union { float f; uint32_t u; } v; v.f = f;
  uint32_t r = v.u + 0x7FFFu + ((v.u >> 16) & 1u);
  return (unsigned short)(r >> 16);
}

// NOTE: the intrinsic's offset arg applies to BOTH global and LDS address
// (R6 failure: absmax 984). Keep it 0 always.
DEV void gl_lds16(const void* g, void* l) {
  __builtin_amdgcn_global_load_lds(
      (const __attribute__((address_space(1))) void*)g,
      (__attribute__((address_space(3))) void*)l, 16, 0, 0);
}

DEV void barx() {
  asm volatile("" ::: "memory");
  __builtin_amdgcn_s_barrier();
  asm volatile("" ::: "memory");
}

#define VMC(N) asm volatile("s_waitcnt vmcnt(" #N ")" ::: "memory")

// exact-gelu via branch-free A&S 7.1.26 erf (max err 1.5e-7)
DEV float gelu_f(float x) {
  const float y = x * 0.7071067811865475f;
  const float ay = fabsf(y);
  const float t = __builtin_amdgcn_rcpf(1.0f + 0.3275911f * ay);
  float p = fmaf(t, 1.061405429f, -1.453152027f);
  p = fmaf(t, p, 1.421413741f);
  p = fmaf(t, p, -0.284496736f);
  p = fmaf(t, p, 0.254829592f);
  p *= t;
  const float e = __expf(-ay * ay);
  float erfv = 1.0f - p * e;
  erfv = copysignf(erfv, y);
  return 0.5f * x * (1.0f + erfv);
}

// ---------------- fused weight fp32 -> bf16 ----------------
__global__ __launch_bounds__(256) void cvt_all(const float* __restrict__ w0, unsigned short* __restrict__ o0,
                                               const float* __restrict__ w1, unsigned short* __restrict__ o1,
                                               const float* __restrict__ w2, unsigned short* __restrict__ o2,
                                               const float* __restrict__ w3, unsigned short* __restrict__ o3) {
  int i = blockIdx.x * 256 + threadIdx.x;
  const float* in; unsigned short* outp;
  if (i < 786432) { in = w0; outp = o0; }
  else if (i < 1048576) { in = w1; outp = o1; i -= 786432; }
  else if (i < 2097152) { in = w2; outp = o2; i -= 1048576; }
  else { in = w3; outp = o3; i -= 2097152; }
  float4 v = ((const float4*)in)[i];
  ushort4 o;
  o.x = f2bf(v.x); o.y = f2bf(v.y); o.z = f2bf(v.z); o.w = f2bf(v.w);
  ((ushort4*)outp)[i] = o;
}

// ---------------- layernorm fp32 -> bf16 (1024 cols, wave per row) ----------------
__global__ __launch_bounds__(256) void ln_kernel(const float* __restrict__ x,
                                                 const float* __restrict__ g,
                                                 const float* __restrict__ b,
                                                 unsigned short* __restrict__ outp) {
  const int row = blockIdx.x * 4 + (threadIdx.x >> 6);
  const int lane = threadIdx.x & 63;
  const float4* xr = (const float4*)(x + (size_t)row * 1024);
  float4 v[4];
  float s = 0.f, s2 = 0.f;
#pragma unroll
  for (int j = 0; j < 4; ++j) {
    v[j] = xr[j * 64 + lane];
    s += v[j].x + v[j].y + v[j].z + v[j].w;
    s2 += v[j].x * v[j].x + v[j].y * v[j].y + v[j].z * v[j].z + v[j].w * v[j].w;
  }
#pragma unroll
  for (int off = 1; off < 64; off <<= 1) {
    s += __shfl_xor(s, off, 64);
    s2 += __shfl_xor(s2, off, 64);
  }
  const float mu = s * (1.0f / 1024.0f);
  const float var = s2 * (1.0f / 1024.0f) - mu * mu;
  const float rstd = rsqrtf(var + 1e-5f);
  ushort4* orow = (ushort4*)(outp + (size_t)row * 1024);
  const float4* gp = (const float4*)g;
  const float4* bp = (const float4*)b;
#pragma unroll
  for (int j = 0; j < 4; ++j) {
    float4 gv = gp[j * 64 + lane], bv = bp[j * 64 + lane];
    ushort4 o;
    o.x = f2bf((v[j].x - mu) * rstd * gv.x + bv.x);
    o.y = f2bf((v[j].y - mu) * rstd * gv.y + bv.y);
    o.z = f2bf((v[j].z - mu) * rstd * gv.z + bv.z);
    o.w = f2bf((v[j].w - mu) * rstd * gv.w + bv.w);
    orow[j * 64 + lane] = o;
  }
}

// ---------------- gemm_bt4: R1 skeleton + counted-vmcnt 4-buffer pipeline -------
// IDENTICAL tile/wave/swizzle/epilogue to the proven gemm_bt (BK=32, 256 thr,
// wave tile BM/2 x 64). ONE change: __syncthreads (vmcnt(0) drain) replaced by
// raw s_barrier + uniform counted vmcnt; 4 LDS buffers, prefetch distance 3.
//   prologue: issue tiles 0,1,2 (U units each, FIFO)
//   iter kt:  VMC(2U)   -> retires exactly tile kt (kt+1,kt+2 stay in flight)
//             barrier   -> all waves' tile-kt DMA landed
//             ds_read buf[kt&3]; issue tile kt+3 -> buf[(kt+3)&3] (last read
//             at iter kt-1, before the PREVIOUS barrier -> WAR-safe); MFMA
//   tail: clamped-but-always-issued (uniform FIFO count); VMC(0) before endpgm.
// U = gl_lds16 per thread per tile: BM=64 -> 3 (VMC 6); BM=128 -> 4 (VMC 8).
// MODE 0: bf16 C; V-third (col>=2048) transposed to Vt[b,h,d,t]   (QKV)
// MODE 1: fp32 C = acc + res                                      (proj + residual)
// MODE 3: fp32 C = acc + bias + res                               (FF2 + residual)
template <int MODE, int BM>
__global__ __launch_bounds__(256) void gemm_bt4(const unsigned short* __restrict__ A,
                                                const unsigned short* __restrict__ B,
                                                float* __restrict__ Cf,
                                                unsigned short* __restrict__ Cb,
                                                const float* __restrict__ bias,
                                                const float* __restrict__ res,
                                                unsigned short* __restrict__ Vt,
                                                int M, int N, int K) {
  constexpr int MI = BM / 32;
  constexpr int RT = 8192 / BM;
  constexpr int ABUF = BM * 32;
  __shared__ unsigned short sA[4][ABUF];
  __shared__ unsigned short sB[4][128 * 32];
  const int tid = threadIdx.x;
  const int w = tid >> 6, lane = tid & 63;
  const int kg = lane >> 4, l16 = lane & 15;
  const int wm = (w & 1) * (BM / 2), wn = (w >> 1) * 64;

  const int cid = blockIdx.y * gridDim.x + blockIdx.x;
  const int colBase = (cid / RT) * 128;
  const int rowBase = (cid % RT) * BM;

  const int sr = (BM == 128) ? (tid >> 2) : ((tid >> 2) & 63);
  const int gc = ((tid & 3) ^ ((sr >> 1) & 3)) * 8;
  const unsigned short* gA = A + (size_t)(rowBase + sr) * K + gc;
  const unsigned short* gB = B + (size_t)(colBase + sr) * K + gc;

  f32x4_t acc[MI][4];
#pragma unroll
  for (int mi = 0; mi < MI; ++mi)
#pragma unroll
    for (int ni = 0; ni < 4; ++ni) acc[mi][ni] = (f32x4_t)0.0f;

  int offA[MI], offB[4];
  const int pc = (kg ^ ((l16 >> 1) & 3)) * 8;
#pragma unroll
  for (int i = 0; i < MI; ++i) offA[i] = (wm + i * 16 + l16) * 32 + pc;
#pragma unroll
  for (int i = 0; i < 4; ++i) offB[i] = (wn + i * 16 + l16) * 32 + pc;

  // prologue: tiles 0,1,2 in FIFO order
#pragma unroll
  for (int t = 0; t < 3; ++t) {
    gl_lds16(gA + (size_t)t * 32, &sA[t][tid * 8]);
    if (BM == 128) gl_lds16(gA + (size_t)64 * K + (size_t)t * 32, &sA[t][2048 + tid * 8]);
    gl_lds16(gB + (size_t)t * 32, &sB[t][tid * 8]);
    gl_lds16(gB + (size_t)64 * K + (size_t)t * 32, &sB[t][2048 + tid * 8]);
  }

  const int nk = K >> 5;
  for (int kt = 0; kt < nk; ++kt) {
    if constexpr (BM == 128) { VMC(8); } else { VMC(6); }
    barx();
    const int par = kt & 3;
    bf16x8_t a[MI], b[4];
#pragma unroll
    for (int i = 0; i < MI; ++i) a[i] = *(const bf16x8_t*)(&sA[par][0] + offA[i]);
#pragma unroll
    for (int i = 0; i < 4; ++i) b[i] = *(const bf16x8_t*)(&sB[par][0] + offB[i]);
    {
      const int t3 = (kt + 3 < nk) ? kt + 3 : nk - 1;
      const int nb = (kt + 3) & 3;
      gl_lds16(gA + (size_t)t3 * 32, &sA[nb][tid * 8]);
      if (BM == 128) gl_lds16(gA + (size_t)64 * K + (size_t)t3 * 32, &sA[nb][2048 + tid * 8]);
      gl_lds16(gB + (size_t)t3 * 32, &sB[nb][tid * 8]);
      gl_lds16(gB + (size_t)64 * K + (size_t)t3 * 32, &sB[nb][2048 + tid * 8]);
    }
#pragma unroll
    for (int mi = 0; mi < MI; ++mi)
#pragma unroll
      for (int ni = 0; ni < 4; ++ni)
        acc[mi][ni] = __builtin_amdgcn_mfma_f32_16x16x32_bf16(a[mi], b[ni], acc[mi][ni], 0, 0, 0);
  }

#pragma unroll
  for (int mi = 0; mi < MI; ++mi) {
#pragma unroll
    for (int ni = 0; ni < 4; ++ni) {
      const int col = colBase + wn + ni * 16 + l16;
      if (MODE == 0 && colBase >= 2048) {
        const int c2 = col - 2048;
        const int hh = c2 >> 6, dd = c2 & 63;
        const int rw = rowBase + wm + mi * 16 + kg * 4;
        ushort4 pk;
        pk.x = f2bf(acc[mi][ni][0]);
        pk.y = f2bf(acc[mi][ni][1]);
        pk.z = f2bf(acc[mi][ni][2]);
        pk.w = f2bf(acc[mi][ni][3]);
        *(ushort4*)(Vt + (((size_t)(rw >> 9) * 16 + hh) * 64 + dd) * 512 + (rw & 511)) = pk;
        continue;
      }
      float bv = 0.f;
      if (MODE == 2 || MODE == 3) bv = bias[col];
#pragma unroll
      for (int r = 0; r < 4; ++r) {
        const int row = rowBase + wm + mi * 16 + kg * 4 + r;
        const size_t idx = (size_t)row * N + col;
        float v = acc[mi][ni][r];
        if (MODE == 0) {
          Cb[idx] = f2bf(v);
        } else if (MODE == 1) {
          Cf[idx] = v + res[idx];
        } else if (MODE == 2) {
          Cb[idx] = f2bf(gelu_f(v + bv));
        } else {
          Cf[idx] = v + bv + res[idx];
        }
      }
    }
  }
  // drain in-flight LDS DMA before LDS dealloc at endpgm
  asm volatile("s_waitcnt vmcnt(0)" ::: "memory");
}

// ---------------- R3-measured deep-pipelined 256x256 GEMM (used for FF1 only) ----
// 512 threads = 8 waves (2M x 4N); per-wave 128x64 (acc[8][4]); BK=64; LDS 128KB dbuf.
// Fragment ds_reads issued ONE PHASE AHEAD of their MFMA, one barrier per phase.
// DMA issued AFTER each MFMA cluster. Measured on FF1: 108.8 us vs 117.8 (R1).
#define RD_AF(DST, BUF, MH, PC)                                               \
  _Pragma("unroll") for (int mi = 0; mi < 4; ++mi)                            \
      DST[mi] = *(const bf16x8_t*)((BUF) + (wm + (MH)*64 + mi * 16 + l16) * 64 + (PC));

#define RD_BF(DST, BUF, PC)                                                   \
  _Pragma("unroll") for (int ni = 0; ni < 4; ++ni)                            \
      DST[ni] = *(const bf16x8_t*)((BUF) + (wn + ni * 16 + l16) * 64 + (PC));

#define MFMA16(MH, AA, BB)                                                    \
  __builtin_amdgcn_s_setprio(1);                                              \
  _Pragma("unroll") for (int mi = 0; mi < 4; ++mi)                            \
  _Pragma("unroll") for (int ni = 0; ni < 4; ++ni)                            \
      acc[(MH)*4 + mi][ni] = __builtin_amdgcn_mfma_f32_16x16x32_bf16(         \
          AA[mi], BB[ni], acc[(MH)*4 + mi][ni], 0, 0, 0);                     \
  __builtin_amdgcn_s_setprio(0);

#define DMA_A(BUF, Q, KT) gl_lds16(aBase + (size_t)((Q)*64) * lda + (size_t)(KT)*64, &sA[BUF][(Q)*4096 + sdo])
#define DMA_B(BUF, Q, KT) gl_lds16(bBase + (size_t)((Q)*64) * lda + (size_t)(KT)*64, &sB[BUF][(Q)*4096 + sdo])

#define TILE(T, CB, B0c, B1c, B0n)                                            \
  {                                                                           \
    const int t1 = ((T) + 1 < nt) ? (T) + 1 : nt - 1;                         \
    const int t2 = ((T) + 2 < nt) ? (T) + 2 : nt - 1;                         \
    const unsigned short* pA = &sA[CB][0];                                    \
    const unsigned short* pB = &sB[CB][0];                                    \
    /* PH0 */                                                                 \
    barx(); VMC(8);                                                           \
    RD_AF(aO, pA, 0, pc1) RD_BF(B1c, pB, pc1)                                 \
    MFMA16(0, aE, B0c)                                                        \
    DMA_A(CB ^ 1, 1, t1); DMA_A(CB ^ 1, 3, t1);                               \
    /* PH1 */                                                                 \
    barx(); VMC(8);                                                           \
    RD_AF(aE, pA, 1, pc0)                                                     \
    MFMA16(0, aO, B1c)                                                        \
    DMA_B(CB, 0, t2); DMA_B(CB, 1, t2);                                       \
    /* PH2 */                                                                 \
    barx();                                                                   \
    RD_AF(aO, pA, 1, pc1)                                                     \
    MFMA16(1, aE, B0c)                                                        \
    DMA_A(CB, 0, t2); DMA_A(CB, 2, t2);                                       \
    /* PH3 */                                                                 \
    barx(); VMC(6);                                                           \
    RD_AF(aE, &sA[CB ^ 1][0], 0, pc0) RD_BF(B0n, &sB[CB ^ 1][0], pc0)         \
    MFMA16(1, aO, B1c)                                                        \
    DMA_B(CB, 2, t2); DMA_B(CB, 3, t2);                                       \
  }

template <int MODE>
__global__ __launch_bounds__(512) void gemm8(const unsigned short* __restrict__ A,
                                             const unsigned short* __restrict__ B,
                                             float* __restrict__ Cf,
                                             unsigned short* __restrict__ Cb,
                                             const float* __restrict__ bias,
                                             const float* __restrict__ res,
                                             unsigned short* __restrict__ Vt,
                                             int M, int N, int K, int lda) {
  __shared__ unsigned short sA[2][256 * 64];
  __shared__ unsigned short sB[2][256 * 64];
  const int tid = threadIdx.x;
  const int w = tid >> 6, lane = tid & 63;
  const int kg = lane >> 4, l16 = lane & 15;
  const int wm = (w & 1) * 128, wn = (w >> 1) * 64;

  const int nwg = gridDim.x;
  const int bid = blockIdx.x;
  const int cid = (bid & 7) * (nwg >> 3) + (bid >> 3);
  const int rowBase = (cid & 31) * 256;
  const int colBase = (cid >> 5) * 256;

  const int srow = tid >> 3, sch = tid & 7;
  const unsigned short* aBase = A + (size_t)(rowBase + srow) * lda + ((sch ^ (srow & 7)) * 8);
  const unsigned short* bBase = B + (size_t)(colBase + srow) * lda + ((sch ^ (srow & 7)) * 8);
  const int sdo = tid * 8;

  f32x4_t acc[8][4];
#pragma unroll
  for (int mi = 0; mi < 8; ++mi)
#pragma unroll
    for (int ni = 0; ni < 4; ++ni) acc[mi][ni] = (f32x4_t)0.0f;

  const int nt = K >> 6;
  const int pc0 = ((kg ^ (l16 & 7)) & 7) * 8;
  const int pc1 = (((4 + kg) ^ (l16 & 7)) & 7) * 8;

  bf16x8_t aE[4], aO[4], B0a[4], B1a[4], B0b[4], B1b[4];

  // prologue: A(0),B(0) full; A(1) q0,q2; B(1) full  (14 units)
  {
    const int t1p = 1 < nt ? 1 : 0;
#pragma unroll
    for (int q = 0; q < 4; ++q) DMA_A(0, q, 0);
#pragma unroll
    for (int q = 0; q < 4; ++q) DMA_B(0, q, 0);
    DMA_A(1, 0, t1p); DMA_A(1, 2, t1p);
#pragma unroll
    for (int q = 0; q < 4; ++q) DMA_B(1, q, t1p);
  }
  VMC(6);
  barx();
  RD_AF(aE, &sA[0][0], 0, pc0)
  RD_BF(B0a, &sB[0][0], pc0)

  for (int t = 0; t < nt; t += 2) {
    TILE(t, 0, B0a, B1a, B0b)
    TILE(t + 1, 1, B0b, B1b, B0a)
  }

  // epilogue
#pragma unroll
  for (int mi = 0; mi < 8; ++mi) {
#pragma unroll
    for (int ni = 0; ni < 4; ++ni) {
      const int col = colBase + wn + ni * 16 + l16;
      float bv = 0.f;
      if (MODE == 2 || MODE == 3) bv = bias[col];
#pragma unroll
      for (int r = 0; r < 4; ++r) {
        const int row = rowBase + wm + mi * 16 + kg * 4 + r;
        const size_t idx = (size_t)row * N + col;
        float v = acc[mi][ni][r];
        if (MODE == 0) {
          Cb[idx] = f2bf(v);
        } else if (MODE == 1) {
          Cf[idx] = v + res[idx];
        } else if (MODE == 2) {
          Cb[idx] = f2bf(gelu_f(v + bv));
        } else {
          Cf[idx] = v + bv + res[idx];
        }
      }
    }
  }
  asm volatile("s_waitcnt vmcnt(0)" ::: "memory");
}

// ---------------- causal flash attention ----------------
// qkv: [8192, 3072] bf16 (q | k cols; V comes from Vt[b,h,d,t]); out: [8192, 1024] bf16
// sQ/sK/sVt XOR-swizzled: physical chunk for (row r, chunk c in 0..7) = c ^ (r&7)
// Softmax WITHOUT max-subtraction. Row-sum l comes FREE from the PV MFMA with an
// all-ones B fragment. qi reversed: heavy causal tiles dispatch first.
__global__ __launch_bounds__(256) void attn_kernel(const unsigned short* __restrict__ qkv,
                                                   const unsigned short* __restrict__ Vt,
                                                   unsigned short* __restrict__ outp) {
  constexpr int D3 = 3072;
  __shared__ unsigned short sQ[128 * 64];
  __shared__ unsigned short sK[64 * 64];
  __shared__ unsigned short sVt[64 * 64];
  __shared__ unsigned short sP[128 * 72];
  const int tid = threadIdx.x;
  const int w = tid >> 6, lane = tid & 63;
  const int kg = lane >> 4, l16 = lane & 15;
  const int qi = (int)gridDim.x - 1 - (int)blockIdx.x;
  const int h = blockIdx.y, bb = blockIdx.z;
  const int t0 = qi * 128;
  const size_t base = (size_t)bb * 512 * D3 + h * 64;

  const int sr = tid >> 3;
  const int sc = ((tid & 7) ^ (sr & 7)) * 8;

  {
    const unsigned short* g = qkv + base + (size_t)(t0 + sr) * D3 + sc;
    unsigned short* l = sQ + tid * 8;
#pragma unroll
    for (int i = 0; i < 4; ++i) gl_lds16(g + (size_t)32 * i * D3, l + 2048 * i);
  }

  const unsigned short* gVbase = Vt + ((size_t)(bb * 16 + h) * 64 + sr) * 512 + sc;

  bf16x8_t ones;
#pragma unroll
  for (int j = 0; j < 8; ++j) ones[j] = (__bf16)1.0f;

  const int wm = w * 32;
  f32x4_t o[2][4];
  f32x4_t lsum[2];
#pragma unroll
  for (int mi = 0; mi < 2; ++mi) {
    lsum[mi] = (f32x4_t)0.0f;
#pragma unroll
    for (int di = 0; di < 4; ++di) o[mi][di] = (f32x4_t)0.0f;
  }

  const int nkt = (qi + 1) * 2;
  for (int kt = 0; kt < nkt; ++kt) {
    const int k0 = kt * 64;
    __syncthreads();
    {
      const unsigned short* g = qkv + base + 1024 + (size_t)(k0 + sr) * D3 + sc;
      unsigned short* l = sK + tid * 8;
      gl_lds16(g, l);
      gl_lds16(g + (size_t)32 * D3, l + 2048);
    }
    {
      const unsigned short* g = gVbase + k0;
      unsigned short* l = sVt + tid * 8;
      gl_lds16(g, l);
      gl_lds16(g + (size_t)32 * 512, l + 2048);
    }
    __syncthreads();

    const bool active = (k0 <= t0 + wm + 31);
    if (active) {
      f32x4_t s[2][4];
#pragma unroll
      for (int mi = 0; mi < 2; ++mi)
#pragma unroll
        for (int ni = 0; ni < 4; ++ni) s[mi][ni] = (f32x4_t)0.0f;
#pragma unroll
      for (int kd = 0; kd < 2; ++kd) {
        bf16x8_t aq[2], bk[4];
#pragma unroll
        for (int mi = 0; mi < 2; ++mi) {
          const int rr = wm + mi * 16 + l16;
          aq[mi] = *(const bf16x8_t*)(sQ + rr * 64 + (((kd * 4 + kg) ^ (l16 & 7)) * 8));
        }
#pragma unroll
        for (int ni = 0; ni < 4; ++ni) {
          const int rr = ni * 16 + l16;
          bk[ni] = *(const bf16x8_t*)(sK + rr * 64 + (((kd * 4 + kg) ^ (l16 & 7)) * 8));
        }
#pragma unroll
        for (int mi = 0; mi < 2; ++mi)
#pragma unroll
          for (int ni = 0; ni < 4; ++ni)
            s[mi][ni] = __builtin_amdgcn_mfma_f32_16x16x32_bf16(aq[mi], bk[ni], s[mi][ni], 0, 0, 0);
      }
#pragma unroll
      for (int mi = 0; mi < 2; ++mi) {
#pragma unroll
        for (int r = 0; r < 4; ++r) {
          const int q = t0 + wm + mi * 16 + kg * 4 + r;
          const int prow = wm + mi * 16 + kg * 4 + r;
#pragma unroll
          for (int ni = 0; ni < 4; ++ni) {
            const int kk = k0 + ni * 16 + l16;
            const float p = (kk <= q) ? __expf(s[mi][ni][r] * 0.125f) : 0.0f;
            sP[prow * 72 + ni * 16 + l16] = f2bf(p);
          }
        }
      }
#pragma unroll
      for (int kd = 0; kd < 2; ++kd) {
        bf16x8_t ap[2], bv[4];
#pragma unroll
        for (int mi = 0; mi < 2; ++mi)
          ap[mi] = *(const bf16x8_t*)(sP + (wm + mi * 16 + l16) * 72 + kd * 32 + kg * 8);
#pragma unroll
        for (int di = 0; di < 4; ++di) {
          const int dd = di * 16 + l16;
          bv[di] = *(const bf16x8_t*)(sVt + dd * 64 + (((kd * 4 + kg) ^ (l16 & 7)) * 8));
        }
#pragma unroll
        for (int mi = 0; mi < 2; ++mi) {
#pragma unroll
          for (int di = 0; di < 4; ++di)
            o[mi][di] = __builtin_amdgcn_mfma_f32_16x16x32_bf16(ap[mi], bv[di], o[mi][di], 0, 0, 0);
          lsum[mi] = __builtin_amdgcn_mfma_f32_16x16x32_bf16(ap[mi], ones, lsum[mi], 0, 0, 0);
        }
      }
    }
  }

#pragma unroll
  for (int mi = 0; mi < 2; ++mi) {
#pragma unroll
    for (int r = 0; r < 4; ++r) {
      const float inv = 1.0f / lsum[mi][r];
      const int row = t0 + wm + mi * 16 + kg * 4 + r;
      const size_t ob = ((size_t)bb * 512 + row) * 1024 + h * 64;
#pragma unroll
      for (int di = 0; di < 4; ++di)
        outp[ob + di * 16 + l16] = f2bf(o[mi][di][r] * inv);
    }
  }
}

// ---------------- launch ----------------
extern "C" void kernel_launch(void* const* d_in, const int* in_sizes, int n_in,
                              void* d_out, int out_size, void* d_ws, size_t ws_size,
                              hipStream_t stream) {
  const float* x      = (const float*)d_in[0];
  const float* w_qkv  = (const float*)d_in[1];
  const float* w_proj = (const float*)d_in[2];
  const float* w_ff1  = (const float*)d_in[3];
  const float* b_ff1  = (const float*)d_in[4];
  const float* w_ff2  = (const float*)d_in[5];
  const float* b_ff2  = (const float*)d_in[6];
  const float* ln1_g  = (const float*)d_in[7];
  const float* ln1_b  = (const float*)d_in[8];
  const float* ln2_g  = (const float*)d_in[9];
  const float* ln2_b  = (const float*)d_in[10];
  float* out = (float*)d_out;
  char* ws = (char*)d_ws;

  // workspace layout (bytes)
  unsigned short* wqkv_b  = (unsigned short*)(ws + 0);          //  6291456
  unsigned short* wproj_b = (unsigned short*)(ws + 6291456);    //  2097152
  unsigned short* wff1_b  = (unsigned short*)(ws + 8388608);    //  8388608
  unsigned short* wff2_b  = (unsigned short*)(ws + 16777216);   //  8388608
  unsigned short* a_b     = (unsigned short*)(ws + 25165824);   // 16777216 (ln1 out, reused for ln2 out)
  float*          x2_f    = (float*)(ws + 41943040);            // 33554432 (dead until proj)
  unsigned short* vt_b    = (unsigned short*)(ws + 41943040);   // 16777216 alias: live QKV->attn only
  unsigned short* qkv_b   = (unsigned short*)(ws + 75497472);   // 50331648
  unsigned short* attn_b  = (unsigned short*)(ws + 125829120);  // 16777216
  unsigned short* h_b     = qkv_b;                              // 67108864 spans qkv+attn (both dead by FF1)

  // weights fp32 -> bf16 (one fused launch)
  cvt_all<<<12288, 256, 0, stream>>>(w_qkv, wqkv_b, w_proj, wproj_b, w_ff1, wff1_b, w_ff2, wff2_b);

  // LN1
  ln_kernel<<<2048, 256, 0, stream>>>(x, ln1_g, ln1_b, a_b);
  // QKV (V third written transposed to vt_b)
  gemm_bt4<0, 128><<<dim3(24, 64), 256, 0, stream>>>(a_b, wqkv_b, nullptr, qkv_b, nullptr, nullptr, vt_b, 8192, 3072, 1024);
  // attention
  attn_kernel<<<dim3(4, 16, 16), 256, 0, stream>>>(qkv_b, vt_b, attn_b);
  // proj + residual (BM=64 -> 1024 blocks)
  gemm_bt4<1, 64><<<dim3(8, 128), 256, 0, stream>>>(attn_b, wproj_b, x2_f, nullptr, nullptr, x, nullptr, 8192, 1024, 1024);
  // LN2
  ln_kernel<<<2048, 256, 0, stream>>>(x2_f, ln2_g, ln2_b, a_b);
  // FF1 + bias + gelu: R3-measured gemm8 (108.8 us vs 117.8 in gemm_bt)
  gemm8<2><<<512, 512, 0, stream>>>(a_b, wff1_b, nullptr, h_b, b_ff1, nullptr, nullptr, 8192, 4096, 1024, 1024);
  // FF2 + bias + residual (BM=64 -> 1024 blocks)
  gemm_bt4<3, 64><<<dim3(8, 128), 256, 0, stream>>>(h_b, wff2_b, out, nullptr, b_ff2, x2_f, nullptr, 8192, 1024, 4096);
}

// Round 7
// 463.493 us; speedup vs baseline: 1.0726x; 1.0726x over previous
//
#include <hip/hip_runtime.h>
#include <stdint.h>

typedef __bf16 bf16x8_t __attribute__((ext_vector_type(8)));
typedef float f32x4_t __attribute__((ext_vector_type(4)));

#define DEV __device__ __forceinline__

DEV unsigned short f2bf(float f) {
  union { float f; uint32_t u; } v; v.f = f;
  uint32_t r = v.u + 0x7FFFu + ((v.u >> 16) & 1u);
  return (unsigned short)(r >> 16);
}

// NOTE: the intrinsic's offset arg applies to BOTH global and LDS address
// (R6 failure: absmax 984). Keep it 0 always.
DEV void gl_lds16(const void* g, void* l) {
  __builtin_amdgcn_global_load_lds(
      (const __attribute__((address_space(1))) void*)g,
      (__attribute__((address_space(3))) void*)l, 16, 0, 0);
}

DEV void barx() {
  asm volatile("" ::: "memory");
  __builtin_amdgcn_s_barrier();
  asm volatile("" ::: "memory");
}

#define VMC(N) asm volatile("s_waitcnt vmcnt(" #N ")" ::: "memory")

// exact-gelu via branch-free A&S 7.1.26 erf (max err 1.5e-7)
DEV float gelu_f(float x) {
  const float y = x * 0.7071067811865475f;
  const float ay = fabsf(y);
  const float t = __builtin_amdgcn_rcpf(1.0f + 0.3275911f * ay);
  float p = fmaf(t, 1.061405429f, -1.453152027f);
  p = fmaf(t, p, 1.421413741f);
  p = fmaf(t, p, -0.284496736f);
  p = fmaf(t, p, 0.254829592f);
  p *= t;
  const float e = __expf(-ay * ay);
  float erfv = 1.0f - p * e;
  erfv = copysignf(erfv, y);
  return 0.5f * x * (1.0f + erfv);
}

// ---------------- fused weight fp32 -> bf16 ----------------
__global__ __launch_bounds__(256) void cvt_all(const float* __restrict__ w0, unsigned short* __restrict__ o0,
                                               const float* __restrict__ w1, unsigned short* __restrict__ o1,
                                               const float* __restrict__ w2, unsigned short* __restrict__ o2,
                                               const float* __restrict__ w3, unsigned short* __restrict__ o3) {
  int i = blockIdx.x * 256 + threadIdx.x;
  const float* in; unsigned short* outp;
  if (i < 786432) { in = w0; outp = o0; }
  else if (i < 1048576) { in = w1; outp = o1; i -= 786432; }
  else if (i < 2097152) { in = w2; outp = o2; i -= 1048576; }
  else { in = w3; outp = o3; i -= 2097152; }
  float4 v = ((const float4*)in)[i];
  ushort4 o;
  o.x = f2bf(v.x); o.y = f2bf(v.y); o.z = f2bf(v.z); o.w = f2bf(v.w);
  ((ushort4*)outp)[i] = o;
}

// ---------------- layernorm fp32 -> bf16 (1024 cols, wave per row) ----------------
__global__ __launch_bounds__(256) void ln_kernel(const float* __restrict__ x,
                                                 const float* __restrict__ g,
                                                 const float* __restrict__ b,
                                                 unsigned short* __restrict__ outp) {
  const int row = blockIdx.x * 4 + (threadIdx.x >> 6);
  const int lane = threadIdx.x & 63;
  const float4* xr = (const float4*)(x + (size_t)row * 1024);
  float4 v[4];
  float s = 0.f, s2 = 0.f;
#pragma unroll
  for (int j = 0; j < 4; ++j) {
    v[j] = xr[j * 64 + lane];
    s += v[j].x + v[j].y + v[j].z + v[j].w;
    s2 += v[j].x * v[j].x + v[j].y * v[j].y + v[j].z * v[j].z + v[j].w * v[j].w;
  }
#pragma unroll
  for (int off = 1; off < 64; off <<= 1) {
    s += __shfl_xor(s, off, 64);
    s2 += __shfl_xor(s2, off, 64);
  }
  const float mu = s * (1.0f / 1024.0f);
  const float var = s2 * (1.0f / 1024.0f) - mu * mu;
  const float rstd = rsqrtf(var + 1e-5f);
  ushort4* orow = (ushort4*)(outp + (size_t)row * 1024);
  const float4* gp = (const float4*)g;
  const float4* bp = (const float4*)b;
#pragma unroll
  for (int j = 0; j < 4; ++j) {
    float4 gv = gp[j * 64 + lane], bv = bp[j * 64 + lane];
    ushort4 o;
    o.x = f2bf((v[j].x - mu) * rstd * gv.x + bv.x);
    o.y = f2bf((v[j].y - mu) * rstd * gv.y + bv.y);
    o.z = f2bf((v[j].z - mu) * rstd * gv.z + bv.z);
    o.w = f2bf((v[j].w - mu) * rstd * gv.w + bv.w);
    orow[j * 64 + lane] = o;
  }
}

// ---------------- GEMM (R1-proven): C[M,N] = A[M,K] * B[N,K]^T, bf16 in ----------
// BK=32, double-buffered LDS, one barrier per iter. BM=128 for large-N GEMMs;
// BM=64 for N=1024 GEMMs (1024 blocks = 4/CU). Swizzle: phys chunk = kc^((row>>1)&3).
// Column-major block order: consecutive blocks share one 128-col B-stripe.
// R6 lesson: occupancy IS the latency-hiding here — 4-buf counted-vmcnt variant
// (48KB LDS, 2 blocks/CU) lost 16% on FF2. Do not spend LDS on pipeline depth.
// MODE 0: bf16 C; V-third (col>=2048) transposed to Vt[b,h,d,t]   (QKV)
// MODE 1: fp32 C = acc + res                                      (proj + residual)
// MODE 3: fp32 C = acc + bias + res                               (FF2 + residual)
template <int MODE, int BM>
__global__ __launch_bounds__(256) void gemm_bt(const unsigned short* __restrict__ A,
                                               const unsigned short* __restrict__ B,
                                               float* __restrict__ Cf,
                                               unsigned short* __restrict__ Cb,
                                               const float* __restrict__ bias,
                                               const float* __restrict__ res,
                                               unsigned short* __restrict__ Vt,
                                               int M, int N, int K) {
  constexpr int MI = BM / 32;
  constexpr int RT = 8192 / BM;
  constexpr int ABUF = BM * 32;
  __shared__ unsigned short sA[2][ABUF];
  __shared__ unsigned short sB[2][128 * 32];
  const int tid = threadIdx.x;
  const int w = tid >> 6, lane = tid & 63;
  const int kg = lane >> 4, l16 = lane & 15;
  const int wm = (w & 1) * (BM / 2), wn = (w >> 1) * 64;

  const int cid = blockIdx.y * gridDim.x + blockIdx.x;
  const int colBase = (cid / RT) * 128;
  const int rowBase = (cid % RT) * BM;

  const int sr = (BM == 128) ? (tid >> 2) : ((tid >> 2) & 63);
  const int gc = ((tid & 3) ^ ((sr >> 1) & 3)) * 8;
  const unsigned short* gA = A + (size_t)(rowBase + sr) * K + gc;
  const unsigned short* gB = B + (size_t)(colBase + sr) * K + gc;

  f32x4_t acc[MI][4];
#pragma unroll
  for (int mi = 0; mi < MI; ++mi)
#pragma unroll
    for (int ni = 0; ni < 4; ++ni) acc[mi][ni] = (f32x4_t)0.0f;

  int offA[MI], offB[4];
  const int pc = (kg ^ ((l16 >> 1) & 3)) * 8;
#pragma unroll
  for (int i = 0; i < MI; ++i) offA[i] = (wm + i * 16 + l16) * 32 + pc;
#pragma unroll
  for (int i = 0; i < 4; ++i) offB[i] = (wn + i * 16 + l16) * 32 + pc;

  gl_lds16(gA, &sA[0][tid * 8]);
  if (BM == 128) gl_lds16(gA + (size_t)64 * K, &sA[0][2048 + tid * 8]);
  gl_lds16(gB, &sB[0][tid * 8]);
  gl_lds16(gB + (size_t)64 * K, &sB[0][2048 + tid * 8]);
  gA += 32; gB += 32;

  const int nk = K >> 5;
  for (int kt = 0; kt < nk; ++kt) {
    __syncthreads();
    if (kt + 1 < nk) {
      const int nb = (kt + 1) & 1;
      gl_lds16(gA, &sA[nb][tid * 8]);
      if (BM == 128) gl_lds16(gA + (size_t)64 * K, &sA[nb][2048 + tid * 8]);
      gl_lds16(gB, &sB[nb][tid * 8]);
      gl_lds16(gB + (size_t)64 * K, &sB[nb][2048 + tid * 8]);
      gA += 32; gB += 32;
    }
    const int par = kt & 1;
    bf16x8_t a[MI], b[4];
#pragma unroll
    for (int i = 0; i < MI; ++i) a[i] = *(const bf16x8_t*)(&sA[par][0] + offA[i]);
#pragma unroll
    for (int i = 0; i < 4; ++i) b[i] = *(const bf16x8_t*)(&sB[par][0] + offB[i]);
#pragma unroll
    for (int mi = 0; mi < MI; ++mi)
#pragma unroll
      for (int ni = 0; ni < 4; ++ni)
        acc[mi][ni] = __builtin_amdgcn_mfma_f32_16x16x32_bf16(a[mi], b[ni], acc[mi][ni], 0, 0, 0);
  }

#pragma unroll
  for (int mi = 0; mi < MI; ++mi) {
#pragma unroll
    for (int ni = 0; ni < 4; ++ni) {
      const int col = colBase + wn + ni * 16 + l16;
      if (MODE == 0 && colBase >= 2048) {
        const int c2 = col - 2048;
        const int hh = c2 >> 6, dd = c2 & 63;
        const int rw = rowBase + wm + mi * 16 + kg * 4;
        ushort4 pk;
        pk.x = f2bf(acc[mi][ni][0]);
        pk.y = f2bf(acc[mi][ni][1]);
        pk.z = f2bf(acc[mi][ni][2]);
        pk.w = f2bf(acc[mi][ni][3]);
        *(ushort4*)(Vt + (((size_t)(rw >> 9) * 16 + hh) * 64 + dd) * 512 + (rw & 511)) = pk;
        continue;
      }
      float bv = 0.f;
      if (MODE == 2 || MODE == 3) bv = bias[col];
#pragma unroll
      for (int r = 0; r < 4; ++r) {
        const int row = rowBase + wm + mi * 16 + kg * 4 + r;
        const size_t idx = (size_t)row * N + col;
        float v = acc[mi][ni][r];
        if (MODE == 0) {
          Cb[idx] = f2bf(v);
        } else if (MODE == 1) {
          Cf[idx] = v + res[idx];
        } else if (MODE == 2) {
          Cb[idx] = f2bf(gelu_f(v + bv));
        } else {
          Cf[idx] = v + bv + res[idx];
        }
      }
    }
  }
}

// ---------------- R3-measured deep-pipelined 256x256 GEMM (used for FF1 only) ----
// 512 threads = 8 waves (2M x 4N); per-wave 128x64 (acc[8][4]); BK=64; LDS 128KB dbuf.
// Fragment ds_reads issued ONE PHASE AHEAD of their MFMA, one barrier per phase.
// DMA issued AFTER each MFMA cluster. Measured on FF1: 108.8 us vs 117.8 (R1).
#define RD_AF(DST, BUF, MH, PC)                                               \
  _Pragma("unroll") for (int mi = 0; mi < 4; ++mi)                            \
      DST[mi] = *(const bf16x8_t*)((BUF) + (wm + (MH)*64 + mi * 16 + l16) * 64 + (PC));

#define RD_BF(DST, BUF, PC)                                                   \
  _Pragma("unroll") for (int ni = 0; ni < 4; ++ni)                            \
      DST[ni] = *(const bf16x8_t*)((BUF) + (wn + ni * 16 + l16) * 64 + (PC));

#define MFMA16(MH, AA, BB)                                                    \
  __builtin_amdgcn_s_setprio(1);                                              \
  _Pragma("unroll") for (int mi = 0; mi < 4; ++mi)                            \
  _Pragma("unroll") for (int ni = 0; ni < 4; ++ni)                            \
      acc[(MH)*4 + mi][ni] = __builtin_amdgcn_mfma_f32_16x16x32_bf16(         \
          AA[mi], BB[ni], acc[(MH)*4 + mi][ni], 0, 0, 0);                     \
  __builtin_amdgcn_s_setprio(0);

#define DMA_A(BUF, Q, KT) gl_lds16(aBase + (size_t)((Q)*64) * lda + (size_t)(KT)*64, &sA[BUF][(Q)*4096 + sdo])
#define DMA_B(BUF, Q, KT) gl_lds16(bBase + (size_t)((Q)*64) * lda + (size_t)(KT)*64, &sB[BUF][(Q)*4096 + sdo])

#define TILE(T, CB, B0c, B1c, B0n)                                            \
  {                                                                           \
    const int t1 = ((T) + 1 < nt) ? (T) + 1 : nt - 1;                         \
    const int t2 = ((T) + 2 < nt) ? (T) + 2 : nt - 1;                         \
    const unsigned short* pA = &sA[CB][0];                                    \
    const unsigned short* pB = &sB[CB][0];                                    \
    /* PH0 */                                                                 \
    barx(); VMC(8);                                                           \
    RD_AF(aO, pA, 0, pc1) RD_BF(B1c, pB, pc1)                                 \
    MFMA16(0, aE, B0c)                                                        \
    DMA_A(CB ^ 1, 1, t1); DMA_A(CB ^ 1, 3, t1);                               \
    /* PH1 */                                                                 \
    barx(); VMC(8);                                                           \
    RD_AF(aE, pA, 1, pc0)                                                     \
    MFMA16(0, aO, B1c)                                                        \
    DMA_B(CB, 0, t2); DMA_B(CB, 1, t2);                                       \
    /* PH2 */                                                                 \
    barx();                                                                   \
    RD_AF(aO, pA, 1, pc1)                                                     \
    MFMA16(1, aE, B0c)                                                        \
    DMA_A(CB, 0, t2); DMA_A(CB, 2, t2);                                       \
    /* PH3 */                                                                 \
    barx(); VMC(6);                                                           \
    RD_AF(aE, &sA[CB ^ 1][0], 0, pc0) RD_BF(B0n, &sB[CB ^ 1][0], pc0)         \
    MFMA16(1, aO, B1c)                                                        \
    DMA_B(CB, 2, t2); DMA_B(CB, 3, t2);                                       \
  }

template <int MODE>
__global__ __launch_bounds__(512) void gemm8(const unsigned short* __restrict__ A,
                                             const unsigned short* __restrict__ B,
                                             float* __restrict__ Cf,
                                             unsigned short* __restrict__ Cb,
                                             const float* __restrict__ bias,
                                             const float* __restrict__ res,
                                             unsigned short* __restrict__ Vt,
                                             int M, int N, int K, int lda) {
  __shared__ unsigned short sA[2][256 * 64];
  __shared__ unsigned short sB[2][256 * 64];
  const int tid = threadIdx.x;
  const int w = tid >> 6, lane = tid & 63;
  const int kg = lane >> 4, l16 = lane & 15;
  const int wm = (w & 1) * 128, wn = (w >> 1) * 64;

  const int nwg = gridDim.x;
  const int bid = blockIdx.x;
  const int cid = (bid & 7) * (nwg >> 3) + (bid >> 3);
  const int rowBase = (cid & 31) * 256;
  const int colBase = (cid >> 5) * 256;

  const int srow = tid >> 3, sch = tid & 7;
  const unsigned short* aBase = A + (size_t)(rowBase + srow) * lda + ((sch ^ (srow & 7)) * 8);
  const unsigned short* bBase = B + (size_t)(colBase + srow) * lda + ((sch ^ (srow & 7)) * 8);
  const int sdo = tid * 8;

  f32x4_t acc[8][4];
#pragma unroll
  for (int mi = 0; mi < 8; ++mi)
#pragma unroll
    for (int ni = 0; ni < 4; ++ni) acc[mi][ni] = (f32x4_t)0.0f;

  const int nt = K >> 6;
  const int pc0 = ((kg ^ (l16 & 7)) & 7) * 8;
  const int pc1 = (((4 + kg) ^ (l16 & 7)) & 7) * 8;

  bf16x8_t aE[4], aO[4], B0a[4], B1a[4], B0b[4], B1b[4];

  // prologue: A(0),B(0) full; A(1) q0,q2; B(1) full  (14 units)
  {
    const int t1p = 1 < nt ? 1 : 0;
#pragma unroll
    for (int q = 0; q < 4; ++q) DMA_A(0, q, 0);
#pragma unroll
    for (int q = 0; q < 4; ++q) DMA_B(0, q, 0);
    DMA_A(1, 0, t1p); DMA_A(1, 2, t1p);
#pragma unroll
    for (int q = 0; q < 4; ++q) DMA_B(1, q, t1p);
  }
  VMC(6);
  barx();
  RD_AF(aE, &sA[0][0], 0, pc0)
  RD_BF(B0a, &sB[0][0], pc0)

  for (int t = 0; t < nt; t += 2) {
    TILE(t, 0, B0a, B1a, B0b)
    TILE(t + 1, 1, B0b, B1b, B0a)
  }

  // epilogue
#pragma unroll
  for (int mi = 0; mi < 8; ++mi) {
#pragma unroll
    for (int ni = 0; ni < 4; ++ni) {
      const int col = colBase + wn + ni * 16 + l16;
      float bv = 0.f;
      if (MODE == 2 || MODE == 3) bv = bias[col];
#pragma unroll
      for (int r = 0; r < 4; ++r) {
        const int row = rowBase + wm + mi * 16 + kg * 4 + r;
        const size_t idx = (size_t)row * N + col;
        float v = acc[mi][ni][r];
        if (MODE == 0) {
          Cb[idx] = f2bf(v);
        } else if (MODE == 1) {
          Cf[idx] = v + res[idx];
        } else if (MODE == 2) {
          Cb[idx] = f2bf(gelu_f(v + bv));
        } else {
          Cf[idx] = v + bv + res[idx];
        }
      }
    }
  }
  asm volatile("s_waitcnt vmcnt(0)" ::: "memory");
}

// ---------------- causal flash attention (K/V double-buffered) ----------------
// qkv: [8192, 3072] bf16 (q | k cols; V comes from Vt[b,h,d,t]); out: [8192, 1024] bf16
// sQ/sK/sVt XOR-swizzled: physical chunk for (row r, chunk c in 0..7) = c ^ (r&7)
// Softmax WITHOUT max-subtraction. Row-sum l comes FREE from the PV MFMA with an
// all-ones B fragment. qi reversed: heavy causal tiles dispatch first.
// R7: K/V double-buffered, ONE __syncthreads per tile, stage AFTER barrier:
//   sync (drains stage(kt) + all waves' compute(kt-1) LDS reads done)
//   -> issue stage(kt+1) into buf[(kt+1)&1]  (WAR-safe: readers passed barrier)
//   -> compute(kt) from buf[kt&1]            (RAW-safe: drained by this sync)
// DMA latency for tile kt+1 hides under compute(kt). sP is per-wave rows only
// (wave w writes/reads rows wm..wm+31) -> no barrier needed around it.
__global__ __launch_bounds__(256) void attn_kernel(const unsigned short* __restrict__ qkv,
                                                   const unsigned short* __restrict__ Vt,
                                                   unsigned short* __restrict__ outp) {
  constexpr int D3 = 3072;
  __shared__ unsigned short sQ[128 * 64];
  __shared__ unsigned short sK[2][64 * 64];
  __shared__ unsigned short sVt[2][64 * 64];
  __shared__ unsigned short sP[128 * 72];
  const int tid = threadIdx.x;
  const int w = tid >> 6, lane = tid & 63;
  const int kg = lane >> 4, l16 = lane & 15;
  const int qi = (int)gridDim.x - 1 - (int)blockIdx.x;
  const int h = blockIdx.y, bb = blockIdx.z;
  const int t0 = qi * 128;
  const size_t base = (size_t)bb * 512 * D3 + h * 64;

  const int sr = tid >> 3;
  const int sc = ((tid & 7) ^ (sr & 7)) * 8;

  // stage Q (rows t0..t0+127)
  {
    const unsigned short* g = qkv + base + (size_t)(t0 + sr) * D3 + sc;
    unsigned short* l = sQ + tid * 8;
#pragma unroll
    for (int i = 0; i < 4; ++i) gl_lds16(g + (size_t)32 * i * D3, l + 2048 * i);
  }

  const unsigned short* gKbase = qkv + base + 1024 + (size_t)sr * D3 + sc;
  const unsigned short* gVbase = Vt + ((size_t)(bb * 16 + h) * 64 + sr) * 512 + sc;

  // stage K/V tile 0 -> buf 0
  {
    gl_lds16(gKbase, sK[0] + tid * 8);
    gl_lds16(gKbase + (size_t)32 * D3, sK[0] + 2048 + tid * 8);
    gl_lds16(gVbase, sVt[0] + tid * 8);
    gl_lds16(gVbase + (size_t)32 * 512, sVt[0] + 2048 + tid * 8);
  }

  bf16x8_t ones;
#pragma unroll
  for (int j = 0; j < 8; ++j) ones[j] = (__bf16)1.0f;

  const int wm = w * 32;
  f32x4_t o[2][4];
  f32x4_t lsum[2];
#pragma unroll
  for (int mi = 0; mi < 2; ++mi) {
    lsum[mi] = (f32x4_t)0.0f;
#pragma unroll
    for (int di = 0; di < 4; ++di) o[mi][di] = (f32x4_t)0.0f;
  }

  const int nkt = (qi + 1) * 2;
  for (int kt = 0; kt < nkt; ++kt) {
    const int k0 = kt * 64;
    __syncthreads();  // stage(kt) landed everywhere; compute(kt-1) reads done
    if (kt + 1 < nkt) {
      const int nb = (kt + 1) & 1;
      const size_t ko = (size_t)(kt + 1) * 64;
      gl_lds16(gKbase + ko * D3, sK[nb] + tid * 8);
      gl_lds16(gKbase + (ko + 32) * D3, sK[nb] + 2048 + tid * 8);
      gl_lds16(gVbase + ko, sVt[nb] + tid * 8);
      gl_lds16(gVbase + (size_t)32 * 512 + ko, sVt[nb] + 2048 + tid * 8);
    }
    const int par = kt & 1;
    const unsigned short* pK = sK[par];
    const unsigned short* pV = sVt[par];

    const bool active = (k0 <= t0 + wm + 31);
    if (active) {
      f32x4_t s[2][4];
#pragma unroll
      for (int mi = 0; mi < 2; ++mi)
#pragma unroll
        for (int ni = 0; ni < 4; ++ni) s[mi][ni] = (f32x4_t)0.0f;
#pragma unroll
      for (int kd = 0; kd < 2; ++kd) {
        bf16x8_t aq[2], bk[4];
#pragma unroll
        for (int mi = 0; mi < 2; ++mi) {
          const int rr = wm + mi * 16 + l16;
          aq[mi] = *(const bf16x8_t*)(sQ + rr * 64 + (((kd * 4 + kg) ^ (l16 & 7)) * 8));
        }
#pragma unroll
        for (int ni = 0; ni < 4; ++ni) {
          const int rr = ni * 16 + l16;
          bk[ni] = *(const bf16x8_t*)(pK + rr * 64 + (((kd * 4 + kg) ^ (l16 & 7)) * 8));
        }
#pragma unroll
        for (int mi = 0; mi < 2; ++mi)
#pragma unroll
          for (int ni = 0; ni < 4; ++ni)
            s[mi][ni] = __builtin_amdgcn_mfma_f32_16x16x32_bf16(aq[mi], bk[ni], s[mi][ni], 0, 0, 0);
      }
#pragma unroll
      for (int mi = 0; mi < 2; ++mi) {
#pragma unroll
        for (int r = 0; r < 4; ++r) {
          const int q = t0 + wm + mi * 16 + kg * 4 + r;
          const int prow = wm + mi * 16 + kg * 4 + r;
#pragma unroll
          for (int ni = 0; ni < 4; ++ni) {
            const int kk = k0 + ni * 16 + l16;
            const float p = (kk <= q) ? __expf(s[mi][ni][r] * 0.125f) : 0.0f;
            sP[prow * 72 + ni * 16 + l16] = f2bf(p);
          }
        }
      }
#pragma unroll
      for (int kd = 0; kd < 2; ++kd) {
        bf16x8_t ap[2], bv[4];
#pragma unroll
        for (int mi = 0; mi < 2; ++mi)
          ap[mi] = *(const bf16x8_t*)(sP + (wm + mi * 16 + l16) * 72 + kd * 32 + kg * 8);
#pragma unroll
        for (int di = 0; di < 4; ++di) {
          const int dd = di * 16 + l16;
          bv[di] = *(const bf16x8_t*)(pV + dd * 64 + (((kd * 4 + kg) ^ (l16 & 7)) * 8));
        }
#pragma unroll
        for (int mi = 0; mi < 2; ++mi) {
#pragma unroll
          for (int di = 0; di < 4; ++di)
            o[mi][di] = __builtin_amdgcn_mfma_f32_16x16x32_bf16(ap[mi], bv[di], o[mi][di], 0, 0, 0);
          lsum[mi] = __builtin_amdgcn_mfma_f32_16x16x32_bf16(ap[mi], ones, lsum[mi], 0, 0, 0);
        }
      }
    }
  }

#pragma unroll
  for (int mi = 0; mi < 2; ++mi) {
#pragma unroll
    for (int r = 0; r < 4; ++r) {
      const float inv = 1.0f / lsum[mi][r];
      const int row = t0 + wm + mi * 16 + kg * 4 + r;
      const size_t ob = ((size_t)bb * 512 + row) * 1024 + h * 64;
#pragma unroll
      for (int di = 0; di < 4; ++di)
        outp[ob + di * 16 + l16] = f2bf(o[mi][di][r] * inv);
    }
  }
}

// ---------------- launch ----------------
extern "C" void kernel_launch(void* const* d_in, const int* in_sizes, int n_in,
                              void* d_out, int out_size, void* d_ws, size_t ws_size,
                              hipStream_t stream) {
  const float* x      = (const float*)d_in[0];
  const float* w_qkv  = (const float*)d_in[1];
  const float* w_proj = (const float*)d_in[2];
  const float* w_ff1  = (const float*)d_in[3];
  const float* b_ff1  = (const float*)d_in[4];
  const float* w_ff2  = (const float*)d_in[5];
  const float* b_ff2  = (const float*)d_in[6];
  const float* ln1_g  = (const float*)d_in[7];
  const float* ln1_b  = (const float*)d_in[8];
  const float* ln2_g  = (const float*)d_in[9];
  const float* ln2_b  = (const float*)d_in[10];
  float* out = (float*)d_out;
  char* ws = (char*)d_ws;

  // workspace layout (bytes)
  unsigned short* wqkv_b  = (unsigned short*)(ws + 0);          //  6291456
  unsigned short* wproj_b = (unsigned short*)(ws + 6291456);    //  2097152
  unsigned short* wff1_b  = (unsigned short*)(ws + 8388608);    //  8388608
  unsigned short* wff2_b  = (unsigned short*)(ws + 16777216);   //  8388608
  unsigned short* a_b     = (unsigned short*)(ws + 25165824);   // 16777216 (ln1 out, reused for ln2 out)
  float*          x2_f    = (float*)(ws + 41943040);            // 33554432 (dead until proj)
  unsigned short* vt_b    = (unsigned short*)(ws + 41943040);   // 16777216 alias: live QKV->attn only
  unsigned short* qkv_b   = (unsigned short*)(ws + 75497472);   // 50331648
  unsigned short* attn_b  = (unsigned short*)(ws + 125829120);  // 16777216
  unsigned short* h_b     = qkv_b;                              // 67108864 spans qkv+attn (both dead by FF1)

  // weights fp32 -> bf16 (one fused launch)
  cvt_all<<<12288, 256, 0, stream>>>(w_qkv, wqkv_b, w_proj, wproj_b, w_ff1, wff1_b, w_ff2, wff2_b);

  // LN1
  ln_kernel<<<2048, 256, 0, stream>>>(x, ln1_g, ln1_b, a_b);
  // QKV (V third written transposed to vt_b)
  gemm_bt<0, 128><<<dim3(24, 64), 256, 0, stream>>>(a_b, wqkv_b, nullptr, qkv_b, nullptr, nullptr, vt_b, 8192, 3072, 1024);
  // attention
  attn_kernel<<<dim3(4, 16, 16), 256, 0, stream>>>(qkv_b, vt_b, attn_b);
  // proj + residual (BM=64 -> 1024 blocks, 4/CU)
  gemm_bt<1, 64><<<dim3(8, 128), 256, 0, stream>>>(attn_b, wproj_b, x2_f, nullptr, nullptr, x, nullptr, 8192, 1024, 1024);
  // LN2
  ln_kernel<<<2048, 256, 0, stream>>>(x2_f, ln2_g, ln2_b, a_b);
  // FF1 + bias + gelu: R3-measured gemm8 (108.8 us vs 117.8 in gemm_bt)
  gemm8<2><<<512, 512, 0, stream>>>(a_b, wff1_b, nullptr, h_b, b_ff1, nullptr, nullptr, 8192, 4096, 1024, 1024);
  // FF2 + bias + residual (BM=64 -> 1024 blocks, 4/CU)
  gemm_bt<3, 64><<<dim3(8, 128), 256, 0, stream>>>(h_b, wff2_b, out, nullptr, b_ff2, x2_f, nullptr, 8192, 1024, 4096);
}